// Round 2
// baseline (322.012 us; speedup 1.0000x reference)
//
#include <hip/hip_runtime.h>
#include <stdint.h>

typedef unsigned short u16;
typedef __attribute__((ext_vector_type(8))) short short8;
typedef __attribute__((ext_vector_type(4))) float floatx4;

#define S_LEN 2048
#define NQKV 3072

#if __has_builtin(__builtin_amdgcn_exp2f)
#define EXP2F __builtin_amdgcn_exp2f
#else
#define EXP2F exp2f
#endif

__device__ inline float bf2f(u16 u) {
  union { uint32_t u; float f; } v; v.u = ((uint32_t)u) << 16; return v.f;
}
__device__ inline u16 f2bf(float f) {
  union { float f; uint32_t u; } v; v.f = f;
  uint32_t r = v.u + 0x7fffu + ((v.u >> 16) & 1u);
  return (u16)(r >> 16);
}
__device__ inline void gl2lds16(const u16* g, u16* l) {
  __builtin_amdgcn_global_load_lds((const __attribute__((address_space(1))) uint32_t*)g,
                                   (__attribute__((address_space(3))) uint32_t*)l, 16, 0, 0);
}

// ---------------- cast fp32 -> bf16, 4 elems/thread ----------------
__global__ void cast_k(const float* __restrict__ in, u16* __restrict__ out, int n4) {
  int i = blockIdx.x * 256 + threadIdx.x;
  if (i >= n4) return;
  float4 v = ((const float4*)in)[i];
  ushort4 o;
  o.x = f2bf(v.x); o.y = f2bf(v.y); o.z = f2bf(v.z); o.w = f2bf(v.w);
  ((ushort4*)out)[i] = o;
}

// ---------------- transpose+cast: in fp32 [K][N] -> out bf16 [N][K] ----------------
__global__ void transpose_k(const float* __restrict__ in, u16* __restrict__ out, int K, int N) {
  __shared__ u16 tile[32][33];
  int n0 = blockIdx.x * 32, k0 = blockIdx.y * 32;
  int tx = threadIdx.x, ty = threadIdx.y;  // 32 x 8
#pragma unroll
  for (int i = 0; i < 4; i++)
    tile[ty + 8 * i][tx] = f2bf(in[(size_t)(k0 + ty + 8 * i) * N + n0 + tx]);
  __syncthreads();
#pragma unroll
  for (int i = 0; i < 4; i++)
    out[(size_t)(n0 + ty + 8 * i) * K + k0 + tx] = tile[tx][ty + 8 * i];
}

// ---------------- V transpose: qkv V region [key][d] -> vt [bz][d][key] (bf16) ----------------
__global__ void vtrans_k(const u16* __restrict__ qkv, u16* __restrict__ vt) {
  __shared__ u16 tile[32][33];
  int bk = blockIdx.x * 32, bd = blockIdx.y * 32, bz = blockIdx.z;
  int bb = bz >> 2, kvh = bz & 3;
  const u16* src = qkv + ((size_t)bb * S_LEN) * NQKV + 2560 + kvh * 128;
  u16* dst = vt + (size_t)bz * 128 * 2048;
  int tx = threadIdx.x, ty = threadIdx.y;
#pragma unroll
  for (int i = 0; i < 4; i++)
    tile[ty + 8 * i][tx] = src[(size_t)(bk + ty + 8 * i) * NQKV + bd + tx];
  __syncthreads();
#pragma unroll
  for (int i = 0; i < 4; i++)
    dst[(size_t)(bd + ty + 8 * i) * 2048 + bk + tx] = tile[tx][ty + 8 * i];
}

// ---------------- GEMM (legacy 128x128, used for Wo projection) ----------------
template <bool OUTF32>
__global__ __launch_bounds__(256) void gemm_bt(const u16* __restrict__ A, const u16* __restrict__ Bt,
                                               void* __restrict__ Cv, int M, int N, int K) {
  __shared__ u16 As[128 * 32];
  __shared__ u16 Bs[128 * 32];
  const int m0 = blockIdx.y * 128, n0 = blockIdx.x * 128;
  const int t = threadIdx.x, w = t >> 6, lane = t & 63;
  const int quad = lane >> 4, l16 = lane & 15;
  const int wm = (w >> 1) * 64, wn = (w & 1) * 64;
  const int lrow = lane >> 2, lk = (lane & 3) * 8;
  floatx4 acc[4][4] = {};
  for (int k0 = 0; k0 < K; k0 += 32) {
#pragma unroll
    for (int c = 2 * w; c <= 2 * w + 1; ++c) {
      int row = c * 16 + lrow;
      gl2lds16(A + (size_t)(m0 + row) * K + k0 + lk, As + c * 512 + lane * 8);
      gl2lds16(Bt + (size_t)(n0 + row) * K + k0 + lk, Bs + c * 512 + lane * 8);
    }
    __syncthreads();
    short8 a[4], b[4];
#pragma unroll
    for (int mt = 0; mt < 4; mt++) a[mt] = *(const short8*)(As + (wm + mt * 16 + l16) * 32 + quad * 8);
#pragma unroll
    for (int nt = 0; nt < 4; nt++) b[nt] = *(const short8*)(Bs + (wn + nt * 16 + l16) * 32 + quad * 8);
#pragma unroll
    for (int mt = 0; mt < 4; mt++)
#pragma unroll
      for (int nt = 0; nt < 4; nt++)
        acc[mt][nt] = __builtin_amdgcn_mfma_f32_16x16x32_bf16(a[mt], b[nt], acc[mt][nt], 0, 0, 0);
    __syncthreads();
  }
#pragma unroll
  for (int mt = 0; mt < 4; mt++)
#pragma unroll
    for (int nt = 0; nt < 4; nt++)
#pragma unroll
      for (int r = 0; r < 4; r++) {
        int row = m0 + wm + mt * 16 + quad * 4 + r;
        int col = n0 + wn + nt * 16 + l16;
        if (OUTF32)
          ((float*)Cv)[(size_t)row * N + col] = acc[mt][nt][r];
        else
          ((u16*)Cv)[(size_t)row * N + col] = f2bf(acc[mt][nt][r]);
      }
}

// ---------------- GEMM 256x256 8-phase (T2+T3+T4+T5+T1), bf16 out ----------------
// C[M][N] = A[M][K] * Bt[N][K]^T.  Requires M%256==0, N%256==0, K%64==0,
// grid = (M/256)*(N/256) with grid%8==0 for the XCD swizzle.
// Structure (per guide §5 template, re-derived):
//  - 8 waves (512 thr), wave tile 64x32 per quadrant; quadrants (mh,nh) of the
//    256x256 C tile are the 4 phases of each K-tile (BK=64).
//  - LDS 128 KiB: A[2 buf][2 half][128][64], B same. Slot-XOR swizzle
//    slot' = slot ^ (row&7) applied on the global SOURCE at DMA time (linear
//    dest, rule #21) and on the ds_read side -> 2-way banks = free.
//  - Per phase: 12 ds_read_b128 ; stage ONE half-tile of kt+1 (2 gl2lds,
//    order A0,B0,B1,A1 = first-use order) ; s_barrier ; lgkmcnt(0) ;
//    setprio(1) 16 MFMA setprio(0) ; vmcnt(4) ; s_barrier.
//    vmcnt(4) (= 2 loads/half-tile x 2 newest half-tiles) keeps the pipe
//    counted and never drains to 0 in the main loop (T4). Raw s_barrier (not
//    __syncthreads) so the compiler does not insert a vmcnt(0) drain.
__global__ __launch_bounds__(512, 2) void gemm256_k(const u16* __restrict__ A,
                                                    const u16* __restrict__ Bt,
                                                    u16* __restrict__ C, int N, int K) {
  __shared__ u16 Al[2][2][8192];
  __shared__ u16 Bl[2][2][8192];
  const int TN = N >> 8;
  int flat = blockIdx.x;
  const int cpx = gridDim.x >> 3;  // grid % 8 == 0 guaranteed by launch config
  flat = (flat & 7) * cpx + (flat >> 3);
  const int m0 = (flat / TN) << 8, n0 = (flat % TN) << 8;
  const int t = threadIdx.x, w = t >> 6, lane = t & 63;
  const int quad = lane >> 4, l16 = lane & 15;
  const int wm = w >> 2, wn = w & 3;
  const int sr = t >> 3, sl = t & 7;  // staging: row-in-round, lds slot
  floatx4 acc[2][2][4][2] = {};
  const int NKT = K >> 6;

  // prologue: stage kt0 into buf0 (A0,B0,B1,A1), full drain once
#pragma unroll
  for (int round = 0; round < 2; round++) {
    int r = round * 64 + sr;
    int so = (sl ^ (r & 7)) << 3;
    gl2lds16(A + (size_t)(m0 + r) * K + so, &Al[0][0][0] + round * 4096 + t * 8);
    gl2lds16(Bt + (size_t)(n0 + r) * K + so, &Bl[0][0][0] + round * 4096 + t * 8);
    gl2lds16(Bt + (size_t)(n0 + 128 + r) * K + so, &Bl[0][1][0] + round * 4096 + t * 8);
    gl2lds16(A + (size_t)(m0 + 128 + r) * K + so, &Al[0][1][0] + round * 4096 + t * 8);
  }
  asm volatile("s_waitcnt vmcnt(0)" ::: "memory");
  __builtin_amdgcn_s_barrier();

  for (int kt = 0; kt < NKT; kt++) {
    const int c = kt & 1;
    const u16* Ab = &Al[c][0][0];
    const u16* Bb = &Bl[c][0][0];
    u16* An = &Al[c ^ 1][0][0];
    u16* Bn = &Bl[c ^ 1][0][0];
    const int k1 = (kt + 1) << 6;
    const bool pf = (kt + 1 < NKT);
#pragma unroll
    for (int ph = 0; ph < 4; ph++) {
      const int mh = ph >> 1, nh = ph & 1;
      // ---- ds-read register subtile (12 x ds_read_b128, swizzled) ----
      short8 af[4][2], bf[2][2];
#pragma unroll
      for (int mt = 0; mt < 4; mt++) {
        int ra = wm * 64 + mt * 16 + l16;
        const u16* base = Ab + mh * 8192 + ra * 64;
#pragma unroll
        for (int ks = 0; ks < 2; ks++)
          af[mt][ks] = *(const short8*)(base + (((ks * 4 + quad) ^ (ra & 7)) << 3));
      }
#pragma unroll
      for (int nt = 0; nt < 2; nt++) {
        int rb = wn * 32 + nt * 16 + l16;
        const u16* base = Bb + nh * 8192 + rb * 64;
#pragma unroll
        for (int ks = 0; ks < 2; ks++)
          bf[nt][ks] = *(const short8*)(base + (((ks * 4 + quad) ^ (rb & 7)) << 3));
      }
      // ---- stage one half-tile of kt+1 (order A0,B0,B1,A1) ----
      if (pf) {
        const u16* G;
        u16* L;
        int rbase;
        if (ph == 0)      { G = A;  L = An;        rbase = m0; }
        else if (ph == 1) { G = Bt; L = Bn;        rbase = n0; }
        else if (ph == 2) { G = Bt; L = Bn + 8192; rbase = n0 + 128; }
        else              { G = A;  L = An + 8192; rbase = m0 + 128; }
#pragma unroll
        for (int round = 0; round < 2; round++) {
          int r = round * 64 + sr;
          gl2lds16(G + (size_t)(rbase + r) * K + k1 + ((sl ^ (r & 7)) << 3),
                   L + round * 4096 + t * 8);
        }
      }
      __builtin_amdgcn_s_barrier();
      asm volatile("s_waitcnt lgkmcnt(0)" ::: "memory");
      __builtin_amdgcn_s_setprio(1);
#pragma unroll
      for (int mt = 0; mt < 4; mt++)
#pragma unroll
        for (int nt = 0; nt < 2; nt++)
#pragma unroll
          for (int ks = 0; ks < 2; ks++)
            acc[mh][nh][mt][nt] =
                __builtin_amdgcn_mfma_f32_16x16x32_bf16(af[mt][ks], bf[nt][ks], acc[mh][nh][mt][nt], 0, 0, 0);
      __builtin_amdgcn_s_setprio(0);
      asm volatile("s_waitcnt vmcnt(4)" ::: "memory");
      __builtin_amdgcn_s_barrier();
    }
  }
  // ---- epilogue ----
#pragma unroll
  for (int mh = 0; mh < 2; mh++)
#pragma unroll
    for (int nh = 0; nh < 2; nh++)
#pragma unroll
      for (int mt = 0; mt < 4; mt++)
#pragma unroll
        for (int nt = 0; nt < 2; nt++)
#pragma unroll
          for (int r = 0; r < 4; r++) {
            int row = m0 + mh * 128 + wm * 64 + mt * 16 + quad * 4 + r;
            int col = n0 + nh * 128 + wn * 32 + nt * 16 + l16;
            C[(size_t)row * N + col] = f2bf(acc[mh][nh][mt][nt][r]);
          }
}

// ---------------- RoPE in place on QKV buffer (bf16), Q + K heads only ----------------
__global__ void rope_k(u16* __restrict__ qkv, const int* __restrict__ pos) {
  int idx = blockIdx.x * 256 + threadIdx.x;
  int i = idx & 63;
  int hh = (idx >> 6) % 20;
  int row = idx / (64 * 20);
  int s = row & (S_LEN - 1);
  float p = (float)pos[s];
  float freq = __expf(-(float)i * 0.015625f * 9.210340371976184f);
  float ang = p * freq;
  float c = cosf(ang), sn = sinf(ang);
  int col = (hh < 16) ? hh * 128 : 2048 + (hh - 16) * 128;
  size_t base = (size_t)row * NQKV + col + i;
  float t1 = bf2f(qkv[base]), t2 = bf2f(qkv[base + 64]);
  qkv[base] = f2bf(t1 * c - t2 * sn);
  qkv[base + 64] = f2bf(t2 * c + t1 * sn);
}

// ---------------- Flash attention, causal GQA ----------------
// (unchanged from previous round: XOR bank-deconflict swizzle on K and V,
// DMA double-buffer, one barrier per iter, no max-tracking, MFMA row-sum.)
#define PL_LD 72
__global__ __launch_bounds__(256) void attn_k(const u16* __restrict__ qkv,
                                              const u16* __restrict__ vt,
                                              u16* __restrict__ ctx) {
  __shared__ u16 Kl[2][64 * 128];      // 2 x 16384 B, [key][d] swizzled
  __shared__ u16 Vl[2][128 * 64];      // 2 x 16384 B, [d][key] swizzled
  __shared__ u16 Pl[4][16 * PL_LD];    // 9216 B   (total 74752 B)
  const int p = blockIdx.x;
  const int h = blockIdx.y, bb = blockIdx.z;
  const int kvh = h >> 2;
  const int t = threadIdx.x, w = t >> 6, lane = t & 63;
  const int quad = lane >> 4, l16 = lane & 15;
  const int sx = l16 & 7;              // read-side swizzle key
  const int kkey0 = w * 16 + (lane >> 4);
  const int kslot = lane & 15;
  const int vd0 = w * 32 + (lane >> 3);
  const int vslot = lane & 7;
  const size_t rowbase = (size_t)bb * S_LEN;
  const u16* Kg0 = qkv + rowbase * NQKV + 2048 + kvh * 128;
  const u16* Vg0 = vt + (size_t)(bb * 4 + kvh) * 128 * 2048;
  const float c2 = 0.12751744f;  // (1/sqrt(128)) * log2(e)
  short8 onesf = {16256, 16256, 16256, 16256, 16256, 16256, 16256, 16256};  // bf16 1.0 x8

  for (int phase = 0; phase < 2; phase++) {
    const int qt = phase ? p : 31 - p;  // q-tile index; qt+1 k-iters
    const int rw = qt * 64 + w * 16;    // this wave's first q-row

    short8 qf[4];
#pragma unroll
    for (int ks = 0; ks < 4; ks++)
      qf[ks] = *(const short8*)(qkv + (rowbase + rw + l16) * NQKV + h * 128 + ks * 32 + quad * 8);

    floatx4 acc[8] = {};
    floatx4 accl = {0.f, 0.f, 0.f, 0.f};

    __syncthreads();  // protect buf0 from previous phase's reads
    // prologue DMA: kb=0 -> buffer 0
    {
      const u16* Kg = Kg0;
      const u16* Vg = Vg0;
#pragma unroll
      for (int ii = 0; ii < 4; ii++) {
        int key = kkey0 + ii * 4;
        gl2lds16(Kg + (size_t)key * NQKV + ((kslot ^ (key & 7)) * 8),
                 &Kl[0][0] + w * 2048 + ii * 512 + lane * 8);
      }
#pragma unroll
      for (int ii = 0; ii < 4; ii++) {
        int d = vd0 + ii * 8;
        gl2lds16(Vg + (size_t)d * 2048 + ((vslot ^ (d & 7)) * 8),
                 &Vl[0][0] + w * 2048 + ii * 512 + lane * 8);
      }
    }

    for (int kb = 0; kb <= qt; kb++) {
      const int cur = kb & 1;
      __syncthreads();  // drains DMA for buf[cur]; releases buf[cur^1] reads
      if (kb < qt) {    // prefetch kb+1 into the other buffer, overlapping compute
        const u16* Kg = Kg0 + (size_t)(kb + 1) * 64 * NQKV;
        const u16* Vg = Vg0 + (kb + 1) * 64;
        u16* KlN = &Kl[cur ^ 1][0];
        u16* VlN = &Vl[cur ^ 1][0];
#pragma unroll
        for (int ii = 0; ii < 4; ii++) {
          int key = kkey0 + ii * 4;
          gl2lds16(Kg + (size_t)key * NQKV + ((kslot ^ (key & 7)) * 8),
                   KlN + w * 2048 + ii * 512 + lane * 8);
        }
#pragma unroll
        for (int ii = 0; ii < 4; ii++) {
          int d = vd0 + ii * 8;
          gl2lds16(Vg + (size_t)d * 2048 + ((vslot ^ (d & 7)) * 8),
                   VlN + w * 2048 + ii * 512 + lane * 8);
        }
      }
      const u16* KlB = &Kl[cur][0];
      const u16* VlB = &Vl[cur][0];

      // ---- QK^T ----
      floatx4 sc[4];
#pragma unroll
      for (int nt = 0; nt < 4; nt++) {
        const u16* Krow = KlB + (nt * 16 + l16) * 128;
        short8 kf[4];
#pragma unroll
        for (int ks = 0; ks < 4; ks++)
          kf[ks] = *(const short8*)(Krow + (((ks * 4 + quad) ^ sx) * 8));
        floatx4 s = {0.f, 0.f, 0.f, 0.f};
#pragma unroll
        for (int ks = 0; ks < 4; ks++) s = __builtin_amdgcn_mfma_f32_16x16x32_bf16(qf[ks], kf[ks], s, 0, 0, 0);
        sc[nt] = s;
      }
      // ---- P = exp2(score * c2), causal mask on diagonal block, trunc-pack bf16 ----
      const bool diag = (kb == qt);
#pragma unroll
      for (int nt = 0; nt < 4; nt++)
#pragma unroll
        for (int r = 0; r < 4; r++) {
          float e = EXP2F(sc[nt][r] * c2);
          if (diag) {
            int keyg = kb * 64 + nt * 16 + l16;
            int rowg = rw + quad * 4 + r;
            if (keyg > rowg) e = 0.f;
          }
          Pl[w][(quad * 4 + r) * PL_LD + nt * 16 + l16] = (u16)(__float_as_uint(e) >> 16);
        }
      // ---- PV (+ ones-column row-sum into accl) ----
      short8 pf[2];
#pragma unroll
      for (int kh = 0; kh < 2; kh++)
        pf[kh] = *(const short8*)(&Pl[w][0] + l16 * PL_LD + kh * 32 + quad * 8);
      accl = __builtin_amdgcn_mfma_f32_16x16x32_bf16(pf[0], onesf, accl, 0, 0, 0);
      accl = __builtin_amdgcn_mfma_f32_16x16x32_bf16(pf[1], onesf, accl, 0, 0, 0);
#pragma unroll
      for (int nto = 0; nto < 8; nto++) {
        const u16* Vrow = VlB + (nto * 16 + l16) * 64;
        short8 vf0 = *(const short8*)(Vrow + ((quad ^ sx) * 8));
        short8 vf1 = *(const short8*)(Vrow + (((quad + 4) ^ sx) * 8));
        acc[nto] = __builtin_amdgcn_mfma_f32_16x16x32_bf16(pf[0], vf0, acc[nto], 0, 0, 0);
        acc[nto] = __builtin_amdgcn_mfma_f32_16x16x32_bf16(pf[1], vf1, acc[nto], 0, 0, 0);
      }
    }
    // ---- epilogue for this q-tile ----
#pragma unroll
    for (int r = 0; r < 4; r++) {
      float inv = 1.0f / accl[r];
      int rowg = rw + quad * 4 + r;
#pragma unroll
      for (int nto = 0; nto < 8; nto++) {
        int col = h * 128 + nto * 16 + l16;
        ctx[(rowbase + rowg) * 2048 + col] = f2bf(acc[nto][r] * inv);
      }
    }
  }
}

extern "C" void kernel_launch(void* const* d_in, const int* in_sizes, int n_in,
                              void* d_out, int out_size, void* d_ws, size_t ws_size,
                              hipStream_t stream) {
  const float* x  = (const float*)d_in[0];
  const int* pos  = (const int*)d_in[1];
  const float* Wq = (const float*)d_in[2];
  const float* Wk = (const float*)d_in[3];
  const float* Wv = (const float*)d_in[4];
  const float* Wo = (const float*)d_in[5];
  float* out = (float*)d_out;
  char* ws = (char*)d_ws;
  // ws layout (bf16): Xb[4096][2048] | WT[3072][2048] | WoT[2048][2048] | QKV[4096][3072] | CTX[4096][2048]
  u16* Xb  = (u16*)(ws);
  u16* WT  = (u16*)(ws + 16777216);
  u16* WoT = (u16*)(ws + 29360128);
  u16* QKV = (u16*)(ws + 37748736);
  u16* CTX = (u16*)(ws + 62914560);
  u16* VT  = Xb;  // [B*NKV][128][2048] bf16, 4 MB, reuses Xb after gemm1

  hipLaunchKernelGGL(cast_k, dim3(8192), dim3(256), 0, stream, x, Xb, 2097152);

  dim3 tb(32, 8);
  hipLaunchKernelGGL(transpose_k, dim3(64, 64), tb, 0, stream, Wq, WT, 2048, 2048);
  hipLaunchKernelGGL(transpose_k, dim3(16, 64), tb, 0, stream, Wk, WT + (size_t)2048 * 2048, 2048, 512);
  hipLaunchKernelGGL(transpose_k, dim3(16, 64), tb, 0, stream, Wv, WT + (size_t)2560 * 2048, 2048, 512);
  hipLaunchKernelGGL(transpose_k, dim3(64, 64), tb, 0, stream, Wo, WoT, 2048, 2048);

  // QKV projection: 4096x3072x2048, 256^2 8-phase kernel, grid 16*12=192 (192%8==0)
  hipLaunchKernelGGL(gemm256_k, dim3(192), dim3(512), 0, stream, Xb, WT, QKV, 3072, 2048);
  hipLaunchKernelGGL(rope_k, dim3(20480), dim3(256), 0, stream, QKV, pos);
  hipLaunchKernelGGL(vtrans_k, dim3(64, 4, 8), tb, 0, stream, QKV, VT);
  hipLaunchKernelGGL(attn_k, dim3(16, 16, 2), dim3(256), 0, stream, QKV, VT, CTX);
  hipLaunchKernelGGL(HIP_KERNEL_NAME(gemm_bt<true>), dim3(16, 32), dim3(256), 0, stream,
                     CTX, WoT, (void*)out, 4096, 2048, 2048);
}

// Round 3
// 308.732 us; speedup vs baseline: 1.0430x; 1.0430x over previous
//
#include <hip/hip_runtime.h>
#include <stdint.h>

typedef unsigned short u16;
typedef __attribute__((ext_vector_type(8))) short short8;
typedef __attribute__((ext_vector_type(4))) float floatx4;

#define S_LEN 2048
#define NQKV 3072

#if __has_builtin(__builtin_amdgcn_exp2f)
#define EXP2F __builtin_amdgcn_exp2f
#else
#define EXP2F exp2f
#endif

__device__ inline float bf2f(u16 u) {
  union { uint32_t u; float f; } v; v.u = ((uint32_t)u) << 16; return v.f;
}
__device__ inline u16 f2bf(float f) {
  union { float f; uint32_t u; } v; v.f = f;
  uint32_t r = v.u + 0x7fffu + ((v.u >> 16) & 1u);
  return (u16)(r >> 16);
}
__device__ inline void gl2lds16(const u16* g, u16* l) {
  __builtin_amdgcn_global_load_lds((const __attribute__((address_space(1))) uint32_t*)g,
                                   (__attribute__((address_space(3))) uint32_t*)l, 16, 0, 0);
}

// ---------------- cast fp32 -> bf16, 4 elems/thread ----------------
__global__ void cast_k(const float* __restrict__ in, u16* __restrict__ out, int n4) {
  int i = blockIdx.x * 256 + threadIdx.x;
  if (i >= n4) return;
  float4 v = ((const float4*)in)[i];
  ushort4 o;
  o.x = f2bf(v.x); o.y = f2bf(v.y); o.z = f2bf(v.z); o.w = f2bf(v.w);
  ((ushort4*)out)[i] = o;
}

// ---------------- transpose+cast: in fp32 [K][N] -> out bf16 [N][K] ----------------
__global__ void transpose_k(const float* __restrict__ in, u16* __restrict__ out, int K, int N) {
  __shared__ u16 tile[32][33];
  int n0 = blockIdx.x * 32, k0 = blockIdx.y * 32;
  int tx = threadIdx.x, ty = threadIdx.y;  // 32 x 8
#pragma unroll
  for (int i = 0; i < 4; i++)
    tile[ty + 8 * i][tx] = f2bf(in[(size_t)(k0 + ty + 8 * i) * N + n0 + tx]);
  __syncthreads();
#pragma unroll
  for (int i = 0; i < 4; i++)
    out[(size_t)(n0 + ty + 8 * i) * K + k0 + tx] = tile[tx][ty + 8 * i];
}

// ---------------- V transpose: qkv V region [key][d] -> vt [bz][d][key] (bf16) ----------------
__global__ void vtrans_k(const u16* __restrict__ qkv, u16* __restrict__ vt) {
  __shared__ u16 tile[32][33];
  int bk = blockIdx.x * 32, bd = blockIdx.y * 32, bz = blockIdx.z;
  int bb = bz >> 2, kvh = bz & 3;
  const u16* src = qkv + ((size_t)bb * S_LEN) * NQKV + 2560 + kvh * 128;
  u16* dst = vt + (size_t)bz * 128 * 2048;
  int tx = threadIdx.x, ty = threadIdx.y;
#pragma unroll
  for (int i = 0; i < 4; i++)
    tile[ty + 8 * i][tx] = src[(size_t)(bk + ty + 8 * i) * NQKV + bd + tx];
  __syncthreads();
#pragma unroll
  for (int i = 0; i < 4; i++)
    dst[(size_t)(bd + ty + 8 * i) * 2048 + bk + tx] = tile[tx][ty + 8 * i];
}

// ---------------- GEMM (legacy 128x128, used for Wo projection) ----------------
template <bool OUTF32>
__global__ __launch_bounds__(256) void gemm_bt(const u16* __restrict__ A, const u16* __restrict__ Bt,
                                               void* __restrict__ Cv, int M, int N, int K) {
  __shared__ u16 As[128 * 32];
  __shared__ u16 Bs[128 * 32];
  const int m0 = blockIdx.y * 128, n0 = blockIdx.x * 128;
  const int t = threadIdx.x, w = t >> 6, lane = t & 63;
  const int quad = lane >> 4, l16 = lane & 15;
  const int wm = (w >> 1) * 64, wn = (w & 1) * 64;
  const int lrow = lane >> 2, lk = (lane & 3) * 8;
  floatx4 acc[4][4] = {};
  for (int k0 = 0; k0 < K; k0 += 32) {
#pragma unroll
    for (int c = 2 * w; c <= 2 * w + 1; ++c) {
      int row = c * 16 + lrow;
      gl2lds16(A + (size_t)(m0 + row) * K + k0 + lk, As + c * 512 + lane * 8);
      gl2lds16(Bt + (size_t)(n0 + row) * K + k0 + lk, Bs + c * 512 + lane * 8);
    }
    __syncthreads();
    short8 a[4], b[4];
#pragma unroll
    for (int mt = 0; mt < 4; mt++) a[mt] = *(const short8*)(As + (wm + mt * 16 + l16) * 32 + quad * 8);
#pragma unroll
    for (int nt = 0; nt < 4; nt++) b[nt] = *(const short8*)(Bs + (wn + nt * 16 + l16) * 32 + quad * 8);
#pragma unroll
    for (int mt = 0; mt < 4; mt++)
#pragma unroll
      for (int nt = 0; nt < 4; nt++)
        acc[mt][nt] = __builtin_amdgcn_mfma_f32_16x16x32_bf16(a[mt], b[nt], acc[mt][nt], 0, 0, 0);
    __syncthreads();
  }
#pragma unroll
  for (int mt = 0; mt < 4; mt++)
#pragma unroll
    for (int nt = 0; nt < 4; nt++)
#pragma unroll
      for (int r = 0; r < 4; r++) {
        int row = m0 + wm + mt * 16 + quad * 4 + r;
        int col = n0 + wn + nt * 16 + l16;
        if (OUTF32)
          ((float*)Cv)[(size_t)row * N + col] = acc[mt][nt][r];
        else
          ((u16*)Cv)[(size_t)row * N + col] = f2bf(acc[mt][nt][r]);
      }
}

// ---------------- GEMM 256x256 8-phase (T2+T3+T4+T5+T1), bf16 out ----------------
// C[M][N] = A[M][K] * Bt[N][K]^T.  M%256==0, N%256==0, K%64==0, grid%8==0.
// R2 post-mortem: quadrant phases re-read fragments -> 48 ds_read_b128 per
// wave per K-tile = 2x the geometry minimum; LDS read pipe (85-128 B/cy/CU)
// was the critical path (76us, MfmaUtil 28%). This version reuses fragments
// across quadrant phases (order (0,0)->(0,1)->(1,1)->(1,0)):
//   ph0: read A0(8)+B0(4); ph1: read B1(4) only; ph2: read A1(8) only;
//   ph3: read NOTHING (af=A1, bf[0] live).   -> 24 reads/K-tile/wave (min).
// Staging (A0,B0,B1,A1 at ph0..3) + vmcnt(4) schedule unchanged; the ph2-end
// vmcnt is dropped (ph3 consumes no newly-staged LDS). Slot-XOR swizzle
// (conflicts measured 0 in R2) and raw-barrier structure kept.
__global__ __launch_bounds__(512, 2) void gemm256_k(const u16* __restrict__ A,
                                                    const u16* __restrict__ Bt,
                                                    u16* __restrict__ C, int N, int K) {
  __shared__ u16 Al[2][2][8192];
  __shared__ u16 Bl[2][2][8192];
  const int TN = N >> 8;
  int flat = blockIdx.x;
  const int cpx = gridDim.x >> 3;  // grid % 8 == 0 guaranteed by launch config
  flat = (flat & 7) * cpx + (flat >> 3);
  const int m0 = (flat / TN) << 8, n0 = (flat % TN) << 8;
  const int t = threadIdx.x, w = t >> 6, lane = t & 63;
  const int quad = lane >> 4, l16 = lane & 15;
  const int wm = w >> 2, wn = w & 3;
  const int sr = t >> 3, sl = t & 7;  // staging: row-in-round, lds slot
  floatx4 acc[2][2][4][2] = {};
  const int NKT = K >> 6;

  // per-wave fragment row indices (compile-time swizzle keys derived from them)
  const int ra_l = wm * 64 + l16;  // + mt*16 ; A row within 128-half
  const int rb_l = wn * 32 + l16;  // + nt*16 ; B row within 128-half

  // prologue: stage kt0 into buf0 (A0,B0,B1,A1), full drain once
#pragma unroll
  for (int round = 0; round < 2; round++) {
    int r = round * 64 + sr;
    int so = (sl ^ (r & 7)) << 3;
    gl2lds16(A + (size_t)(m0 + r) * K + so, &Al[0][0][0] + round * 4096 + t * 8);
    gl2lds16(Bt + (size_t)(n0 + r) * K + so, &Bl[0][0][0] + round * 4096 + t * 8);
    gl2lds16(Bt + (size_t)(n0 + 128 + r) * K + so, &Bl[0][1][0] + round * 4096 + t * 8);
    gl2lds16(A + (size_t)(m0 + 128 + r) * K + so, &Al[0][1][0] + round * 4096 + t * 8);
  }
  asm volatile("s_waitcnt vmcnt(0)" ::: "memory");
  __builtin_amdgcn_s_barrier();

  short8 af[4][2];     // current A-half fragments (reused by 2 phases)
  short8 bf[2][2][2];  // [nh][nt][ks] both B-half fragments

  for (int kt = 0; kt < NKT; kt++) {
    const int c = kt & 1;
    const u16* Ab = &Al[c][0][0];
    const u16* Bb = &Bl[c][0][0];
    u16* An = &Al[c ^ 1][0][0];
    u16* Bn = &Bl[c ^ 1][0][0];
    const int k1 = (kt + 1) << 6;
    const bool pf = (kt + 1 < NKT);
#pragma unroll
    for (int ph = 0; ph < 4; ph++) {
      // quadrant sequence: (mh,nh) = (0,0),(0,1),(1,1),(1,0)
      const int mh = (ph >> 1);
      const int nh = (ph == 1 || ph == 2) ? 1 : 0;
      // ---- ds-read ONLY the new fragments for this phase ----
      if (ph == 0 || ph == 2) {  // new A-half
#pragma unroll
        for (int mt = 0; mt < 4; mt++) {
          int ra = ra_l + mt * 16;
          const u16* base = Ab + mh * 8192 + ra * 64;
#pragma unroll
          for (int ks = 0; ks < 2; ks++)
            af[mt][ks] = *(const short8*)(base + (((ks * 4 + quad) ^ (ra & 7)) << 3));
        }
      }
      if (ph == 0 || ph == 1) {  // new B-half
#pragma unroll
        for (int nt = 0; nt < 2; nt++) {
          int rb = rb_l + nt * 16;
          const u16* base = Bb + nh * 8192 + rb * 64;
#pragma unroll
          for (int ks = 0; ks < 2; ks++)
            bf[nh][nt][ks] = *(const short8*)(base + (((ks * 4 + quad) ^ (rb & 7)) << 3));
        }
      }
      // ---- stage one half-tile of kt+1 (order A0,B0,B1,A1) ----
      if (pf) {
        const u16* G;
        u16* L;
        int rbase;
        if (ph == 0)      { G = A;  L = An;        rbase = m0; }
        else if (ph == 1) { G = Bt; L = Bn;        rbase = n0; }
        else if (ph == 2) { G = Bt; L = Bn + 8192; rbase = n0 + 128; }
        else              { G = A;  L = An + 8192; rbase = m0 + 128; }
#pragma unroll
        for (int round = 0; round < 2; round++) {
          int r = round * 64 + sr;
          gl2lds16(G + (size_t)(rbase + r) * K + k1 + ((sl ^ (r & 7)) << 3),
                   L + round * 4096 + t * 8);
        }
      }
      __builtin_amdgcn_s_barrier();
      asm volatile("s_waitcnt lgkmcnt(0)" ::: "memory");
      __builtin_amdgcn_s_setprio(1);
#pragma unroll
      for (int mt = 0; mt < 4; mt++)
#pragma unroll
        for (int nt = 0; nt < 2; nt++)
#pragma unroll
          for (int ks = 0; ks < 2; ks++)
            acc[mh][nh][mt][nt] =
                __builtin_amdgcn_mfma_f32_16x16x32_bf16(af[mt][ks], bf[nh][nt][ks], acc[mh][nh][mt][nt], 0, 0, 0);
      __builtin_amdgcn_s_setprio(0);
      if (ph != 2) asm volatile("s_waitcnt vmcnt(4)" ::: "memory");
      __builtin_amdgcn_s_barrier();
    }
  }
  // ---- epilogue ----
#pragma unroll
  for (int mh = 0; mh < 2; mh++)
#pragma unroll
    for (int nh = 0; nh < 2; nh++)
#pragma unroll
      for (int mt = 0; mt < 4; mt++)
#pragma unroll
        for (int nt = 0; nt < 2; nt++)
#pragma unroll
          for (int r = 0; r < 4; r++) {
            int row = m0 + mh * 128 + wm * 64 + mt * 16 + quad * 4 + r;
            int col = n0 + nh * 128 + wn * 32 + nt * 16 + l16;
            C[(size_t)row * N + col] = f2bf(acc[mh][nh][mt][nt][r]);
          }
}

// ---------------- RoPE in place on QKV buffer (bf16), Q + K heads only ----------------
__global__ void rope_k(u16* __restrict__ qkv, const int* __restrict__ pos) {
  int idx = blockIdx.x * 256 + threadIdx.x;
  int i = idx & 63;
  int hh = (idx >> 6) % 20;
  int row = idx / (64 * 20);
  int s = row & (S_LEN - 1);
  float p = (float)pos[s];
  float freq = __expf(-(float)i * 0.015625f * 9.210340371976184f);
  float ang = p * freq;
  float c = cosf(ang), sn = sinf(ang);
  int col = (hh < 16) ? hh * 128 : 2048 + (hh - 16) * 128;
  size_t base = (size_t)row * NQKV + col + i;
  float t1 = bf2f(qkv[base]), t2 = bf2f(qkv[base + 64]);
  qkv[base] = f2bf(t1 * c - t2 * sn);
  qkv[base + 64] = f2bf(t2 * c + t1 * sn);
}

// ---------------- Flash attention, causal GQA ----------------
// (unchanged: XOR bank-deconflict swizzle on K and V, DMA double-buffer,
// one barrier per iter, no max-tracking, MFMA row-sum.)
#define PL_LD 72
__global__ __launch_bounds__(256) void attn_k(const u16* __restrict__ qkv,
                                              const u16* __restrict__ vt,
                                              u16* __restrict__ ctx) {
  __shared__ u16 Kl[2][64 * 128];      // 2 x 16384 B, [key][d] swizzled
  __shared__ u16 Vl[2][128 * 64];      // 2 x 16384 B, [d][key] swizzled
  __shared__ u16 Pl[4][16 * PL_LD];    // 9216 B   (total 74752 B)
  const int p = blockIdx.x;
  const int h = blockIdx.y, bb = blockIdx.z;
  const int kvh = h >> 2;
  const int t = threadIdx.x, w = t >> 6, lane = t & 63;
  const int quad = lane >> 4, l16 = lane & 15;
  const int sx = l16 & 7;              // read-side swizzle key
  const int kkey0 = w * 16 + (lane >> 4);
  const int kslot = lane & 15;
  const int vd0 = w * 32 + (lane >> 3);
  const int vslot = lane & 7;
  const size_t rowbase = (size_t)bb * S_LEN;
  const u16* Kg0 = qkv + rowbase * NQKV + 2048 + kvh * 128;
  const u16* Vg0 = vt + (size_t)(bb * 4 + kvh) * 128 * 2048;
  const float c2 = 0.12751744f;  // (1/sqrt(128)) * log2(e)
  short8 onesf = {16256, 16256, 16256, 16256, 16256, 16256, 16256, 16256};  // bf16 1.0 x8

  for (int phase = 0; phase < 2; phase++) {
    const int qt = phase ? p : 31 - p;  // q-tile index; qt+1 k-iters
    const int rw = qt * 64 + w * 16;    // this wave's first q-row

    short8 qf[4];
#pragma unroll
    for (int ks = 0; ks < 4; ks++)
      qf[ks] = *(const short8*)(qkv + (rowbase + rw + l16) * NQKV + h * 128 + ks * 32 + quad * 8);

    floatx4 acc[8] = {};
    floatx4 accl = {0.f, 0.f, 0.f, 0.f};

    __syncthreads();  // protect buf0 from previous phase's reads
    // prologue DMA: kb=0 -> buffer 0
    {
      const u16* Kg = Kg0;
      const u16* Vg = Vg0;
#pragma unroll
      for (int ii = 0; ii < 4; ii++) {
        int key = kkey0 + ii * 4;
        gl2lds16(Kg + (size_t)key * NQKV + ((kslot ^ (key & 7)) * 8),
                 &Kl[0][0] + w * 2048 + ii * 512 + lane * 8);
      }
#pragma unroll
      for (int ii = 0; ii < 4; ii++) {
        int d = vd0 + ii * 8;
        gl2lds16(Vg + (size_t)d * 2048 + ((vslot ^ (d & 7)) * 8),
                 &Vl[0][0] + w * 2048 + ii * 512 + lane * 8);
      }
    }

    for (int kb = 0; kb <= qt; kb++) {
      const int cur = kb & 1;
      __syncthreads();  // drains DMA for buf[cur]; releases buf[cur^1] reads
      if (kb < qt) {    // prefetch kb+1 into the other buffer, overlapping compute
        const u16* Kg = Kg0 + (size_t)(kb + 1) * 64 * NQKV;
        const u16* Vg = Vg0 + (kb + 1) * 64;
        u16* KlN = &Kl[cur ^ 1][0];
        u16* VlN = &Vl[cur ^ 1][0];
#pragma unroll
        for (int ii = 0; ii < 4; ii++) {
          int key = kkey0 + ii * 4;
          gl2lds16(Kg + (size_t)key * NQKV + ((kslot ^ (key & 7)) * 8),
                   KlN + w * 2048 + ii * 512 + lane * 8);
        }
#pragma unroll
        for (int ii = 0; ii < 4; ii++) {
          int d = vd0 + ii * 8;
          gl2lds16(Vg + (size_t)d * 2048 + ((vslot ^ (d & 7)) * 8),
                   VlN + w * 2048 + ii * 512 + lane * 8);
        }
      }
      const u16* KlB = &Kl[cur][0];
      const u16* VlB = &Vl[cur][0];

      // ---- QK^T ----
      floatx4 sc[4];
#pragma unroll
      for (int nt = 0; nt < 4; nt++) {
        const u16* Krow = KlB + (nt * 16 + l16) * 128;
        short8 kf[4];
#pragma unroll
        for (int ks = 0; ks < 4; ks++)
          kf[ks] = *(const short8*)(Krow + (((ks * 4 + quad) ^ sx) * 8));
        floatx4 s = {0.f, 0.f, 0.f, 0.f};
#pragma unroll
        for (int ks = 0; ks < 4; ks++) s = __builtin_amdgcn_mfma_f32_16x16x32_bf16(qf[ks], kf[ks], s, 0, 0, 0);
        sc[nt] = s;
      }
      // ---- P = exp2(score * c2), causal mask on diagonal block, trunc-pack bf16 ----
      const bool diag = (kb == qt);
#pragma unroll
      for (int nt = 0; nt < 4; nt++)
#pragma unroll
        for (int r = 0; r < 4; r++) {
          float e = EXP2F(sc[nt][r] * c2);
          if (diag) {
            int keyg = kb * 64 + nt * 16 + l16;
            int rowg = rw + quad * 4 + r;
            if (keyg > rowg) e = 0.f;
          }
          Pl[w][(quad * 4 + r) * PL_LD + nt * 16 + l16] = (u16)(__float_as_uint(e) >> 16);
        }
      // ---- PV (+ ones-column row-sum into accl) ----
      short8 pf[2];
#pragma unroll
      for (int kh = 0; kh < 2; kh++)
        pf[kh] = *(const short8*)(&Pl[w][0] + l16 * PL_LD + kh * 32 + quad * 8);
      accl = __builtin_amdgcn_mfma_f32_16x16x32_bf16(pf[0], onesf, accl, 0, 0, 0);
      accl = __builtin_amdgcn_mfma_f32_16x16x32_bf16(pf[1], onesf, accl, 0, 0, 0);
#pragma unroll
      for (int nto = 0; nto < 8; nto++) {
        const u16* Vrow = VlB + (nto * 16 + l16) * 64;
        short8 vf0 = *(const short8*)(Vrow + ((quad ^ sx) * 8));
        short8 vf1 = *(const short8*)(Vrow + (((quad + 4) ^ sx) * 8));
        acc[nto] = __builtin_amdgcn_mfma_f32_16x16x32_bf16(pf[0], vf0, acc[nto], 0, 0, 0);
        acc[nto] = __builtin_amdgcn_mfma_f32_16x16x32_bf16(pf[1], vf1, acc[nto], 0, 0, 0);
      }
    }
    // ---- epilogue for this q-tile ----
#pragma unroll
    for (int r = 0; r < 4; r++) {
      float inv = 1.0f / accl[r];
      int rowg = rw + quad * 4 + r;
#pragma unroll
      for (int nto = 0; nto < 8; nto++) {
        int col = h * 128 + nto * 16 + l16;
        ctx[(rowbase + rowg) * 2048 + col] = f2bf(acc[nto][r] * inv);
      }
    }
  }
}

extern "C" void kernel_launch(void* const* d_in, const int* in_sizes, int n_in,
                              void* d_out, int out_size, void* d_ws, size_t ws_size,
                              hipStream_t stream) {
  const float* x  = (const float*)d_in[0];
  const int* pos  = (const int*)d_in[1];
  const float* Wq = (const float*)d_in[2];
  const float* Wk = (const float*)d_in[3];
  const float* Wv = (const float*)d_in[4];
  const float* Wo = (const float*)d_in[5];
  float* out = (float*)d_out;
  char* ws = (char*)d_ws;
  // ws layout (bf16): Xb[4096][2048] | WT[3072][2048] | WoT[2048][2048] | QKV[4096][3072] | CTX[4096][2048]
  u16* Xb  = (u16*)(ws);
  u16* WT  = (u16*)(ws + 16777216);
  u16* WoT = (u16*)(ws + 29360128);
  u16* QKV = (u16*)(ws + 37748736);
  u16* CTX = (u16*)(ws + 62914560);
  u16* VT  = Xb;  // [B*NKV][128][2048] bf16, 4 MB, reuses Xb after gemm1

  hipLaunchKernelGGL(cast_k, dim3(8192), dim3(256), 0, stream, x, Xb, 2097152);

  dim3 tb(32, 8);
  hipLaunchKernelGGL(transpose_k, dim3(64, 64), tb, 0, stream, Wq, WT, 2048, 2048);
  hipLaunchKernelGGL(transpose_k, dim3(16, 64), tb, 0, stream, Wk, WT + (size_t)2048 * 2048, 2048, 512);
  hipLaunchKernelGGL(transpose_k, dim3(16, 64), tb, 0, stream, Wv, WT + (size_t)2560 * 2048, 2048, 512);
  hipLaunchKernelGGL(transpose_k, dim3(64, 64), tb, 0, stream, Wo, WoT, 2048, 2048);

  // QKV projection: 4096x3072x2048, 256^2 8-phase kernel, grid 16*12=192 (192%8==0)
  hipLaunchKernelGGL(gemm256_k, dim3(192), dim3(512), 0, stream, Xb, WT, QKV, 3072, 2048);
  hipLaunchKernelGGL(rope_k, dim3(20480), dim3(256), 0, stream, QKV, pos);
  hipLaunchKernelGGL(vtrans_k, dim3(64, 4, 8), tb, 0, stream, QKV, VT);
  hipLaunchKernelGGL(attn_k, dim3(16, 16, 2), dim3(256), 0, stream, QKV, VT, CTX);
  hipLaunchKernelGGL(HIP_KERNEL_NAME(gemm_bt<true>), dim3(16, 32), dim3(256), 0, stream,
                     CTX, WoT, (void*)out, 4096, 2048, 2048);
}

// Round 4
// 304.135 us; speedup vs baseline: 1.0588x; 1.0151x over previous
//
#include <hip/hip_runtime.h>
#include <stdint.h>

typedef unsigned short u16;
typedef __attribute__((ext_vector_type(8))) short short8;
typedef __attribute__((ext_vector_type(4))) float floatx4;

#define S_LEN 2048
#define NQKV 3072

#if __has_builtin(__builtin_amdgcn_exp2f)
#define EXP2F __builtin_amdgcn_exp2f
#else
#define EXP2F exp2f
#endif

__device__ inline float bf2f(u16 u) {
  union { uint32_t u; float f; } v; v.u = ((uint32_t)u) << 16; return v.f;
}
__device__ inline u16 f2bf(float f) {
  union { float f; uint32_t u; } v; v.f = f;
  uint32_t r = v.u + 0x7fffu + ((v.u >> 16) & 1u);
  return (u16)(r >> 16);
}
__device__ inline void gl2lds16(const u16* g, u16* l) {
  __builtin_amdgcn_global_load_lds((const __attribute__((address_space(1))) uint32_t*)g,
                                   (__attribute__((address_space(3))) uint32_t*)l, 16, 0, 0);
}

// ---------------- cast fp32 -> bf16, 4 elems/thread ----------------
__global__ void cast_k(const float* __restrict__ in, u16* __restrict__ out, int n4) {
  int i = blockIdx.x * 256 + threadIdx.x;
  if (i >= n4) return;
  float4 v = ((const float4*)in)[i];
  ushort4 o;
  o.x = f2bf(v.x); o.y = f2bf(v.y); o.z = f2bf(v.z); o.w = f2bf(v.w);
  ((ushort4*)out)[i] = o;
}

// ---------------- transpose+cast: in fp32 [K][N] -> out bf16 [N][K] ----------------
__global__ void transpose_k(const float* __restrict__ in, u16* __restrict__ out, int K, int N) {
  __shared__ u16 tile[32][33];
  int n0 = blockIdx.x * 32, k0 = blockIdx.y * 32;
  int tx = threadIdx.x, ty = threadIdx.y;  // 32 x 8
#pragma unroll
  for (int i = 0; i < 4; i++)
    tile[ty + 8 * i][tx] = f2bf(in[(size_t)(k0 + ty + 8 * i) * N + n0 + tx]);
  __syncthreads();
#pragma unroll
  for (int i = 0; i < 4; i++)
    out[(size_t)(n0 + ty + 8 * i) * K + k0 + tx] = tile[tx][ty + 8 * i];
}

// ---------------- V transpose: qkv V region [key][d] -> vt [bz][d][key] (bf16) ----------------
__global__ void vtrans_k(const u16* __restrict__ qkv, u16* __restrict__ vt) {
  __shared__ u16 tile[32][33];
  int bk = blockIdx.x * 32, bd = blockIdx.y * 32, bz = blockIdx.z;
  int bb = bz >> 2, kvh = bz & 3;
  const u16* src = qkv + ((size_t)bb * S_LEN) * NQKV + 2560 + kvh * 128;
  u16* dst = vt + (size_t)bz * 128 * 2048;
  int tx = threadIdx.x, ty = threadIdx.y;
#pragma unroll
  for (int i = 0; i < 4; i++)
    tile[ty + 8 * i][tx] = src[(size_t)(bk + ty + 8 * i) * NQKV + bd + tx];
  __syncthreads();
#pragma unroll
  for (int i = 0; i < 4; i++)
    dst[(size_t)(bd + ty + 8 * i) * 2048 + bk + tx] = tile[tx][ty + 8 * i];
}

// ---------------- GEMM (legacy 128x128, used for Wo projection) ----------------
template <bool OUTF32>
__global__ __launch_bounds__(256) void gemm_bt(const u16* __restrict__ A, const u16* __restrict__ Bt,
                                               void* __restrict__ Cv, int M, int N, int K) {
  __shared__ u16 As[128 * 32];
  __shared__ u16 Bs[128 * 32];
  const int m0 = blockIdx.y * 128, n0 = blockIdx.x * 128;
  const int t = threadIdx.x, w = t >> 6, lane = t & 63;
  const int quad = lane >> 4, l16 = lane & 15;
  const int wm = (w >> 1) * 64, wn = (w & 1) * 64;
  const int lrow = lane >> 2, lk = (lane & 3) * 8;
  floatx4 acc[4][4] = {};
  for (int k0 = 0; k0 < K; k0 += 32) {
#pragma unroll
    for (int c = 2 * w; c <= 2 * w + 1; ++c) {
      int row = c * 16 + lrow;
      gl2lds16(A + (size_t)(m0 + row) * K + k0 + lk, As + c * 512 + lane * 8);
      gl2lds16(Bt + (size_t)(n0 + row) * K + k0 + lk, Bs + c * 512 + lane * 8);
    }
    __syncthreads();
    short8 a[4], b[4];
#pragma unroll
    for (int mt = 0; mt < 4; mt++) a[mt] = *(const short8*)(As + (wm + mt * 16 + l16) * 32 + quad * 8);
#pragma unroll
    for (int nt = 0; nt < 4; nt++) b[nt] = *(const short8*)(Bs + (wn + nt * 16 + l16) * 32 + quad * 8);
#pragma unroll
    for (int mt = 0; mt < 4; mt++)
#pragma unroll
      for (int nt = 0; nt < 4; nt++)
        acc[mt][nt] = __builtin_amdgcn_mfma_f32_16x16x32_bf16(a[mt], b[nt], acc[mt][nt], 0, 0, 0);
    __syncthreads();
  }
#pragma unroll
  for (int mt = 0; mt < 4; mt++)
#pragma unroll
    for (int nt = 0; nt < 4; nt++)
#pragma unroll
      for (int r = 0; r < 4; r++) {
        int row = m0 + wm + mt * 16 + quad * 4 + r;
        int col = n0 + wn + nt * 16 + l16;
        if (OUTF32)
          ((float*)Cv)[(size_t)row * N + col] = acc[mt][nt][r];
        else
          ((u16*)Cv)[(size_t)row * N + col] = f2bf(acc[mt][nt][r]);
      }
}

// ---------------- GEMM 256x256 8-phase (T2+T3+T4+T5+T1), bf16 out ----------------
// (unchanged from R3: fragment reuse across quadrant phases, 24 ds_read_b128
// per wave per K-tile = geometry minimum; slot-XOR swizzle, counted vmcnt.)
__global__ __launch_bounds__(512, 2) void gemm256_k(const u16* __restrict__ A,
                                                    const u16* __restrict__ Bt,
                                                    u16* __restrict__ C, int N, int K) {
  __shared__ u16 Al[2][2][8192];
  __shared__ u16 Bl[2][2][8192];
  const int TN = N >> 8;
  int flat = blockIdx.x;
  const int cpx = gridDim.x >> 3;  // grid % 8 == 0 guaranteed by launch config
  flat = (flat & 7) * cpx + (flat >> 3);
  const int m0 = (flat / TN) << 8, n0 = (flat % TN) << 8;
  const int t = threadIdx.x, w = t >> 6, lane = t & 63;
  const int quad = lane >> 4, l16 = lane & 15;
  const int wm = w >> 2, wn = w & 3;
  const int sr = t >> 3, sl = t & 7;  // staging: row-in-round, lds slot
  floatx4 acc[2][2][4][2] = {};
  const int NKT = K >> 6;

  const int ra_l = wm * 64 + l16;  // + mt*16 ; A row within 128-half
  const int rb_l = wn * 32 + l16;  // + nt*16 ; B row within 128-half

  // prologue: stage kt0 into buf0 (A0,B0,B1,A1), full drain once
#pragma unroll
  for (int round = 0; round < 2; round++) {
    int r = round * 64 + sr;
    int so = (sl ^ (r & 7)) << 3;
    gl2lds16(A + (size_t)(m0 + r) * K + so, &Al[0][0][0] + round * 4096 + t * 8);
    gl2lds16(Bt + (size_t)(n0 + r) * K + so, &Bl[0][0][0] + round * 4096 + t * 8);
    gl2lds16(Bt + (size_t)(n0 + 128 + r) * K + so, &Bl[0][1][0] + round * 4096 + t * 8);
    gl2lds16(A + (size_t)(m0 + 128 + r) * K + so, &Al[0][1][0] + round * 4096 + t * 8);
  }
  asm volatile("s_waitcnt vmcnt(0)" ::: "memory");
  __builtin_amdgcn_s_barrier();

  short8 af[4][2];     // current A-half fragments (reused by 2 phases)
  short8 bf[2][2][2];  // [nh][nt][ks] both B-half fragments

  for (int kt = 0; kt < NKT; kt++) {
    const int c = kt & 1;
    const u16* Ab = &Al[c][0][0];
    const u16* Bb = &Bl[c][0][0];
    u16* An = &Al[c ^ 1][0][0];
    u16* Bn = &Bl[c ^ 1][0][0];
    const int k1 = (kt + 1) << 6;
    const bool pf = (kt + 1 < NKT);
#pragma unroll
    for (int ph = 0; ph < 4; ph++) {
      // quadrant sequence: (mh,nh) = (0,0),(0,1),(1,1),(1,0)
      const int mh = (ph >> 1);
      const int nh = (ph == 1 || ph == 2) ? 1 : 0;
      // ---- ds-read ONLY the new fragments for this phase ----
      if (ph == 0 || ph == 2) {  // new A-half
#pragma unroll
        for (int mt = 0; mt < 4; mt++) {
          int ra = ra_l + mt * 16;
          const u16* base = Ab + mh * 8192 + ra * 64;
#pragma unroll
          for (int ks = 0; ks < 2; ks++)
            af[mt][ks] = *(const short8*)(base + (((ks * 4 + quad) ^ (ra & 7)) << 3));
        }
      }
      if (ph == 0 || ph == 1) {  // new B-half
#pragma unroll
        for (int nt = 0; nt < 2; nt++) {
          int rb = rb_l + nt * 16;
          const u16* base = Bb + nh * 8192 + rb * 64;
#pragma unroll
          for (int ks = 0; ks < 2; ks++)
            bf[nh][nt][ks] = *(const short8*)(base + (((ks * 4 + quad) ^ (rb & 7)) << 3));
        }
      }
      // ---- stage one half-tile of kt+1 (order A0,B0,B1,A1) ----
      if (pf) {
        const u16* G;
        u16* L;
        int rbase;
        if (ph == 0)      { G = A;  L = An;        rbase = m0; }
        else if (ph == 1) { G = Bt; L = Bn;        rbase = n0; }
        else if (ph == 2) { G = Bt; L = Bn + 8192; rbase = n0 + 128; }
        else              { G = A;  L = An + 8192; rbase = m0 + 128; }
#pragma unroll
        for (int round = 0; round < 2; round++) {
          int r = round * 64 + sr;
          gl2lds16(G + (size_t)(rbase + r) * K + k1 + ((sl ^ (r & 7)) << 3),
                   L + round * 4096 + t * 8);
        }
      }
      __builtin_amdgcn_s_barrier();
      asm volatile("s_waitcnt lgkmcnt(0)" ::: "memory");
      __builtin_amdgcn_s_setprio(1);
#pragma unroll
      for (int mt = 0; mt < 4; mt++)
#pragma unroll
        for (int nt = 0; nt < 2; nt++)
#pragma unroll
          for (int ks = 0; ks < 2; ks++)
            acc[mh][nh][mt][nt] =
                __builtin_amdgcn_mfma_f32_16x16x32_bf16(af[mt][ks], bf[nh][nt][ks], acc[mh][nh][mt][nt], 0, 0, 0);
      __builtin_amdgcn_s_setprio(0);
      if (ph != 2) asm volatile("s_waitcnt vmcnt(4)" ::: "memory");
      __builtin_amdgcn_s_barrier();
    }
  }
  // ---- epilogue ----
#pragma unroll
  for (int mh = 0; mh < 2; mh++)
#pragma unroll
    for (int nh = 0; nh < 2; nh++)
#pragma unroll
      for (int mt = 0; mt < 4; mt++)
#pragma unroll
        for (int nt = 0; nt < 2; nt++)
#pragma unroll
          for (int r = 0; r < 4; r++) {
            int row = m0 + mh * 128 + wm * 64 + mt * 16 + quad * 4 + r;
            int col = n0 + nh * 128 + wn * 32 + nt * 16 + l16;
            C[(size_t)row * N + col] = f2bf(acc[mh][nh][mt][nt][r]);
          }
}

// ---------------- RoPE in place on QKV buffer (bf16), Q + K heads only ----------------
__global__ void rope_k(u16* __restrict__ qkv, const int* __restrict__ pos) {
  int idx = blockIdx.x * 256 + threadIdx.x;
  int i = idx & 63;
  int hh = (idx >> 6) % 20;
  int row = idx / (64 * 20);
  int s = row & (S_LEN - 1);
  float p = (float)pos[s];
  float freq = __expf(-(float)i * 0.015625f * 9.210340371976184f);
  float ang = p * freq;
  float c = cosf(ang), sn = sinf(ang);
  int col = (hh < 16) ? hh * 128 : 2048 + (hh - 16) * 128;
  size_t base = (size_t)row * NQKV + col + i;
  float t1 = bf2f(qkv[base]), t2 = bf2f(qkv[base + 64]);
  qkv[base] = f2bf(t1 * c - t2 * sn);
  qkv[base + 64] = f2bf(t2 * c + t1 * sn);
}

// ---------------- Flash attention, causal GQA ----------------
// R4: P LDS round-trip ELIMINATED (R3 counters: 4.87M residual bank-conflict
// cycles + 18 LDS ops/iter in the P path; LDS pipe = critical path).
// Method: swapped QK^T (mfma(kf,qf)) so lane (quad,l16) holds S[pos][q=l16],
// PLUS a K-row staging permutation kperm(p) = 8*((p>>2)&3) + 4*((p>>4)&1)
// + (p&3) + 32*(p>>5) chosen so the lane's own 16 exp values, trunc-packed
// pairwise in natural order, ARE the PV A-fragments for keys 0-31/32-63
// (index algebra: A[l16][kappa] = P(q, key=kappa) exactly; V column order
// required = identity -> V staging unchanged). Zero cross-lane ops, zero
// LDS transit for P. P values use the same truncation and PV/accl sum keys
// in the same order -> bit-identical output vs R3.
// Causal mask remap: keyg = kb*64 + 8*quad + 4*(nt&1) + 32*(nt>>1) + r;
// q-row = rw + l16. LDS drops 74752 -> 65536 B.
__global__ __launch_bounds__(256) void attn_k(const u16* __restrict__ qkv,
                                              const u16* __restrict__ vt,
                                              u16* __restrict__ ctx) {
  __shared__ u16 Kl[2][64 * 128];      // 2 x 16384 B, [pos][d] swizzled, rows kperm'd
  __shared__ u16 Vl[2][128 * 64];      // 2 x 16384 B, [d][key] swizzled
  const int p = blockIdx.x;
  const int h = blockIdx.y, bb = blockIdx.z;
  const int kvh = h >> 2;
  const int t = threadIdx.x, w = t >> 6, lane = t & 63;
  const int quad = lane >> 4, l16 = lane & 15;
  const int sx = l16 & 7;              // read-side swizzle key
  const int kslot = lane & 15;
  const int vd0 = w * 32 + (lane >> 3);
  const int vslot = lane & 7;
  // K staging: LDS position pos = w*16 + ii*4 + quad holds global key row
  // kperm(pos) = 8*ii + 4*(w&1) + 32*(w>>1) + quad  (bijection, see header).
  const int grow0 = (w & 1) * 4 + (w >> 1) * 32 + quad;
  const size_t rowbase = (size_t)bb * S_LEN;
  const u16* Kg0 = qkv + rowbase * NQKV + 2048 + kvh * 128;
  const u16* Vg0 = vt + (size_t)(bb * 4 + kvh) * 128 * 2048;
  const float c2 = 0.12751744f;  // (1/sqrt(128)) * log2(e)
  short8 onesf = {16256, 16256, 16256, 16256, 16256, 16256, 16256, 16256};  // bf16 1.0 x8

  for (int phase = 0; phase < 2; phase++) {
    const int qt = phase ? p : 31 - p;  // q-tile index; qt+1 k-iters
    const int rw = qt * 64 + w * 16;    // this wave's first q-row
    const int qrow = rw + l16;          // this lane's q-row (swapped layout: col=q)

    short8 qf[4];
#pragma unroll
    for (int ks = 0; ks < 4; ks++)
      qf[ks] = *(const short8*)(qkv + (rowbase + rw + l16) * NQKV + h * 128 + ks * 32 + quad * 8);

    floatx4 acc[8] = {};
    floatx4 accl = {0.f, 0.f, 0.f, 0.f};

    __syncthreads();  // protect buf0 from previous phase's reads
    // prologue DMA: kb=0 -> buffer 0
    {
      const u16* Kg = Kg0;
      const u16* Vg = Vg0;
#pragma unroll
      for (int ii = 0; ii < 4; ii++) {
        int p7 = (quad + 4 * ii) & 7;  // (position)&7 for the slot swizzle
        int grow = grow0 + 8 * ii;     // permuted global key row
        gl2lds16(Kg + (size_t)grow * NQKV + ((kslot ^ p7) * 8),
                 &Kl[0][0] + w * 2048 + ii * 512 + lane * 8);
      }
#pragma unroll
      for (int ii = 0; ii < 4; ii++) {
        int d = vd0 + ii * 8;
        gl2lds16(Vg + (size_t)d * 2048 + ((vslot ^ (d & 7)) * 8),
                 &Vl[0][0] + w * 2048 + ii * 512 + lane * 8);
      }
    }

    for (int kb = 0; kb <= qt; kb++) {
      const int cur = kb & 1;
      __syncthreads();  // drains DMA for buf[cur]; releases buf[cur^1] reads
      if (kb < qt) {    // prefetch kb+1 into the other buffer, overlapping compute
        const u16* Kg = Kg0 + (size_t)(kb + 1) * 64 * NQKV;
        const u16* Vg = Vg0 + (kb + 1) * 64;
        u16* KlN = &Kl[cur ^ 1][0];
        u16* VlN = &Vl[cur ^ 1][0];
#pragma unroll
        for (int ii = 0; ii < 4; ii++) {
          int p7 = (quad + 4 * ii) & 7;
          int grow = grow0 + 8 * ii;
          gl2lds16(Kg + (size_t)grow * NQKV + ((kslot ^ p7) * 8),
                   KlN + w * 2048 + ii * 512 + lane * 8);
        }
#pragma unroll
        for (int ii = 0; ii < 4; ii++) {
          int d = vd0 + ii * 8;
          gl2lds16(Vg + (size_t)d * 2048 + ((vslot ^ (d & 7)) * 8),
                   VlN + w * 2048 + ii * 512 + lane * 8);
        }
      }
      const u16* KlB = &Kl[cur][0];
      const u16* VlB = &Vl[cur][0];

      // ---- QK^T (swapped: A=K, B=Q -> lane holds S[pos=quad*4+r][q=l16]) ----
      floatx4 sc[4];
#pragma unroll
      for (int nt = 0; nt < 4; nt++) {
        const u16* Krow = KlB + (nt * 16 + l16) * 128;
        short8 kf[4];
#pragma unroll
        for (int ks = 0; ks < 4; ks++)
          kf[ks] = *(const short8*)(Krow + (((ks * 4 + quad) ^ sx) * 8));
        floatx4 s = {0.f, 0.f, 0.f, 0.f};
#pragma unroll
        for (int ks = 0; ks < 4; ks++) s = __builtin_amdgcn_mfma_f32_16x16x32_bf16(kf[ks], qf[ks], s, 0, 0, 0);
        sc[nt] = s;
      }
      // ---- P = exp2(score*c2), causal mask, trunc-pack DIRECTLY into A-frags ----
      const bool diag = (kb == qt);
      uint32_t pw[8];
#pragma unroll
      for (int nt = 0; nt < 4; nt++) {
        uint32_t w0 = 0, w1 = 0;
#pragma unroll
        for (int r = 0; r < 4; r++) {
          float e = EXP2F(sc[nt][r] * c2);
          if (diag) {
            int keyg = kb * 64 + quad * 8 + (nt & 1) * 4 + (nt >> 1) * 32 + r;
            if (keyg > qrow) e = 0.f;
          }
          uint32_t b = __float_as_uint(e) >> 16;
          if (r == 0) w0 = b;
          else if (r == 1) w0 |= b << 16;
          else if (r == 2) w1 = b;
          else w1 |= b << 16;
        }
        pw[nt * 2] = w0;
        pw[nt * 2 + 1] = w1;
      }
      union { short8 v; uint32_t u[4]; } pu0, pu1;
      pu0.u[0] = pw[0]; pu0.u[1] = pw[1]; pu0.u[2] = pw[2]; pu0.u[3] = pw[3];
      pu1.u[0] = pw[4]; pu1.u[1] = pw[5]; pu1.u[2] = pw[6]; pu1.u[3] = pw[7];
      const short8 pf0 = pu0.v, pf1 = pu1.v;  // PV A-frags, keys 0-31 / 32-63

      // ---- PV (+ ones-column row-sum into accl) ----
      accl = __builtin_amdgcn_mfma_f32_16x16x32_bf16(pf0, onesf, accl, 0, 0, 0);
      accl = __builtin_amdgcn_mfma_f32_16x16x32_bf16(pf1, onesf, accl, 0, 0, 0);
#pragma unroll
      for (int nto = 0; nto < 8; nto++) {
        const u16* Vrow = VlB + (nto * 16 + l16) * 64;
        short8 vf0 = *(const short8*)(Vrow + ((quad ^ sx) * 8));
        short8 vf1 = *(const short8*)(Vrow + (((quad + 4) ^ sx) * 8));
        acc[nto] = __builtin_amdgcn_mfma_f32_16x16x32_bf16(pf0, vf0, acc[nto], 0, 0, 0);
        acc[nto] = __builtin_amdgcn_mfma_f32_16x16x32_bf16(pf1, vf1, acc[nto], 0, 0, 0);
      }
    }
    // ---- epilogue for this q-tile (D layout unchanged: lane holds O[q=quad*4+r][d=l16]) ----
#pragma unroll
    for (int r = 0; r < 4; r++) {
      float inv = 1.0f / accl[r];
      int rowg = rw + quad * 4 + r;
#pragma unroll
      for (int nto = 0; nto < 8; nto++) {
        int col = h * 128 + nto * 16 + l16;
        ctx[(rowbase + rowg) * 2048 + col] = f2bf(acc[nto][r] * inv);
      }
    }
  }
}

extern "C" void kernel_launch(void* const* d_in, const int* in_sizes, int n_in,
                              void* d_out, int out_size, void* d_ws, size_t ws_size,
                              hipStream_t stream) {
  const float* x  = (const float*)d_in[0];
  const int* pos  = (const int*)d_in[1];
  const float* Wq = (const float*)d_in[2];
  const float* Wk = (const float*)d_in[3];
  const float* Wv = (const float*)d_in[4];
  const float* Wo = (const float*)d_in[5];
  float* out = (float*)d_out;
  char* ws = (char*)d_ws;
  // ws layout (bf16): Xb[4096][2048] | WT[3072][2048] | WoT[2048][2048] | QKV[4096][3072] | CTX[4096][2048]
  u16* Xb  = (u16*)(ws);
  u16* WT  = (u16*)(ws + 16777216);
  u16* WoT = (u16*)(ws + 29360128);
  u16* QKV = (u16*)(ws + 37748736);
  u16* CTX = (u16*)(ws + 62914560);
  u16* VT  = Xb;  // [B*NKV][128][2048] bf16, 4 MB, reuses Xb after gemm1

  hipLaunchKernelGGL(cast_k, dim3(8192), dim3(256), 0, stream, x, Xb, 2097152);

  dim3 tb(32, 8);
  hipLaunchKernelGGL(transpose_k, dim3(64, 64), tb, 0, stream, Wq, WT, 2048, 2048);
  hipLaunchKernelGGL(transpose_k, dim3(16, 64), tb, 0, stream, Wk, WT + (size_t)2048 * 2048, 2048, 512);
  hipLaunchKernelGGL(transpose_k, dim3(16, 64), tb, 0, stream, Wv, WT + (size_t)2560 * 2048, 2048, 512);
  hipLaunchKernelGGL(transpose_k, dim3(64, 64), tb, 0, stream, Wo, WoT, 2048, 2048);

  // QKV projection: 4096x3072x2048, 256^2 8-phase kernel, grid 16*12=192 (192%8==0)
  hipLaunchKernelGGL(gemm256_k, dim3(192), dim3(512), 0, stream, Xb, WT, QKV, 3072, 2048);
  hipLaunchKernelGGL(rope_k, dim3(20480), dim3(256), 0, stream, QKV, pos);
  hipLaunchKernelGGL(vtrans_k, dim3(64, 4, 8), tb, 0, stream, QKV, VT);
  hipLaunchKernelGGL(attn_k, dim3(16, 16, 2), dim3(256), 0, stream, QKV, VT, CTX);
  hipLaunchKernelGGL(HIP_KERNEL_NAME(gemm_bt<true>), dim3(16, 32), dim3(256), 0, stream,
                     CTX, WoT, (void*)out, 4096, 2048, 2048);
}